// Round 4
// baseline (132.637 us; speedup 1.0000x reference)
//
#include <hip/hip_runtime.h>

#define B_TOT 32768
#define OC 30
#define HID 100
#define TAGS 36

// ws layout (dwords):
#define WS_TH  0          // u32[2000]    T2 rows: c*20 + d (d<16 used), k=2 table only
#define WS_TB  2048       // u32[160000]  bigram TB rows: (c0*100+c1)*16 + d  (640 KB)
#define WS_FC1 162048     // u32[13*2048] fc1 B packs, ks-major, 2048-dw stride (1792 used/ks)
#define WS_OUT 188672     // u32[3072]    out B packs, ks-major: chunk = ks*3+nt

typedef __attribute__((ext_vector_type(8))) _Float16 half8;
typedef __attribute__((ext_vector_type(2))) _Float16 h2v;
typedef __attribute__((ext_vector_type(4))) float f32x4;

__device__ inline half8 ash8(uint4 u) {
    union { uint4 a; half8 b; } v; v.a = u; return v.b;
}
__device__ inline unsigned int h2u(h2v h) {
    union { h2v a; unsigned int b; } v; v.a = h; return v.b;
}
__device__ inline h2v u2h(unsigned int u) {
    union { unsigned int a; h2v b; } v; v.a = u; return v.b;
}
__device__ inline unsigned int pk_f16(float a, float b) {
    h2v h; h.x = (_Float16)a; h.y = (_Float16)b; return h2u(h);
}
__device__ inline float fast_tanh(float x) {
    float ax = __builtin_fabsf(x);
    float e  = __expf(2.0f * ax);
    float r  = 1.0f - 2.0f * __builtin_amdgcn_rcpf(e + 1.0f);
    return __builtin_copysignf(r, x);
}

// ---------------- prep: T2 + bigram TB + fp16 MFMA B-frag packs ----------------
__global__ void prep(const float* __restrict__ conv_w,   // (30,32,3)
                     const float* __restrict__ char_emb, // (100,32)
                     const float* __restrict__ fc1_w,    // (100,400)
                     const float* __restrict__ out_w,    // (36,100)
                     unsigned int* __restrict__ ws) {
    int idx = blockIdx.x * 256 + threadIdx.x;
    if (idx < 1600) {
        // T2 (k=2): row c, dword d holds oc pair (2d, 2d+1); row stride 20 dwords
        int d = idx & 15, c = idx >> 4;
        float v[2];
        #pragma unroll
        for (int e = 0; e < 2; ++e) {
            int oc = 2 * d + e;
            float s = 0.f;
            if (oc < OC) {
                for (int ce = 0; ce < 32; ++ce)
                    s += char_emb[c * 32 + ce] * conv_w[(oc * 32 + ce) * 3 + 2];
            }
            v[e] = s;
        }
        ws[WS_TH + c * 20 + d] = pk_f16(v[0], v[1]);
    } else if (idx < 1600 + 160000) {
        // TB bigram: pair (c0,c1), dword d = oc pair; TB = T0[c0] + T1[c1] summed in f32
        int t = idx - 1600;
        int d = t & 15;
        int pair = t >> 4;            // 0..9999
        int c1 = pair % 100, c0 = pair / 100;
        float v[2];
        #pragma unroll
        for (int e = 0; e < 2; ++e) {
            int oc = 2 * d + e;
            float s = 0.f;
            if (oc < OC) {
                for (int ce = 0; ce < 32; ++ce) {
                    s += char_emb[c0 * 32 + ce] * conv_w[(oc * 32 + ce) * 3 + 0]
                       + char_emb[c1 * 32 + ce] * conv_w[(oc * 32 + ce) * 3 + 1];
                }
            }
            v[e] = s;
        }
        ws[WS_TB + pair * 16 + d] = pk_f16(v[0], v[1]);
    } else if (idx < 161600 + 23296) {
        // fc1 B-frag chunks, ks-major: region ks*2048 + (nt*64+lane)*4+dw
        int t = idx - 161600;
        int dw = t & 3, lane = (t >> 2) & 63, chunk = t >> 8;   // chunk 0..90
        int ks = chunk / 7, nt = chunk % 7;
        int j = nt * 16 + (lane & 15);
        int k = ks * 32 + (lane >> 4) * 8 + dw * 2;
        float a = (j < HID && k     < 400) ? fc1_w[j * 400 + k]     : 0.f;
        float b = (j < HID && k + 1 < 400) ? fc1_w[j * 400 + k + 1] : 0.f;
        ws[WS_FC1 + ks * 2048 + (nt * 64 + lane) * 4 + dw] = pk_f16(a, b);
    } else if (idx < 184896 + 3072) {
        // out B-frag chunks, ks-major: chunk = ks*3+nt, linear
        int t = idx - 184896;
        int dw = t & 3, lane = (t >> 2) & 63, chunk = t >> 8;   // chunk 0..11
        int ks = chunk / 3, nt = chunk % 3;
        int j = nt * 16 + (lane & 15);
        int k = ks * 32 + (lane >> 4) * 8 + dw * 2;
        float a = (j < TAGS && k     < HID) ? out_w[j * 100 + k]     : 0.f;
        float b = (j < TAGS && k + 1 < HID) ? out_w[j * 100 + k + 1] : 0.f;
        ws[WS_OUT + t] = pk_f16(a, b);
    }
}

// ---------------- fused: emb+conv(TB global + T2 LDS) -> F in LDS -> fc1 MFMA -> tanh -> out ----------------
__global__ __launch_bounds__(256, 2)
void fused(const int*   __restrict__ input,   // (B, 105)
           const float* __restrict__ emb,     // (WV, 50)
           const float* __restrict__ conv_b,  // (30)
           const float* __restrict__ fc1_b,   // (100)
           const float* __restrict__ out_b,   // (36)
           const unsigned int* __restrict__ ws,
           float*       __restrict__ out)     // (B, 36)
{
    __shared__ __align__(16) unsigned int Ths[4096];      // T2 (2000 dw); after conv: B dbuf [2][512 u4] / out-B
    __shared__ __align__(16) unsigned int FL[64 * 212];   // F rows (212-dw stride)

    const int tid  = threadIdx.x;
    const int wv   = tid >> 6;
    const int lane = tid & 63;
    const int ln15 = lane & 15;
    const int quad = lane >> 4;
    const int gi0  = blockIdx.x * 64 + wv * 16;
    unsigned int* Fw = &FL[wv * (16 * 212)];

    const uint4* srcB = (const uint4*)(ws + WS_FC1);      // uint4 idx: ks*512 + e
    const int se = wv * 128 + lane;                       // this wave's staging slot (+64 for 2nd)

    // ---- stage T2 table (block-wide, vectorized; 8 KB) ----
    {
        const uint4* src = (const uint4*)(ws + WS_TH);
        uint4* dst = (uint4*)Ths;
        for (int idx = tid; idx < 500; idx += 256) dst[idx] = src[idx];
    }
    // prologue B loads for ks=0 (pure global loads, fly during emb/conv)
    uint4 p0 = srcB[se], p1 = srcB[se + 64];
    __syncthreads();

    // ---- zero K-pad dwords 200..207 of this wave's 16 rows ----
    #pragma unroll
    for (int r = 0; r < 2; ++r) {
        int idx = lane + r * 64;
        Fw[(idx >> 3) * 212 + 200 + (idx & 7)] = 0;
    }

    // ---- word embeddings (own 16 items) ----
    #pragma unroll 4
    for (int idx = lane; idx < 2000; idx += 64) {
        int ph = idx % 25;
        int w  = (idx / 25) % 5;
        int i  = idx / 125;
        int wid = input[(gi0 + i) * 105 + w * 21];
        float2 e = *(const float2*)&emb[wid * 50 + ph * 2];
        Fw[i * 212 + w * 40 + ph] = pk_f16(e.x, e.y);
    }

    // ---- conv + maxpool: 4 lanes per (i,w), lane = 8 oc; 5 tasks per lane ----
    {
        const int q4  = lane & 3;
        const int oc0 = q4 * 8;
        h2v bias[4];
        #pragma unroll
        for (int d = 0; d < 4; ++d) {
            int a = oc0 + 2 * d, b = a + 1;
            bias[d].x = (_Float16)(a < OC ? conv_b[a] : 0.f);
            bias[d].y = (_Float16)(b < OC ? conv_b[b] : 0.f);
        }
        const uint4* TBg = (const uint4*)(ws + WS_TB);    // global bigram, row=pair, chunk q4
        const unsigned int* T2 = Ths;                     // row stride 20, chunk q4*4
        #pragma unroll
        for (int it = 0; it < 5; ++it) {
            int task = (lane >> 2) + it * 16;   // 0..79
            int i = task / 5, w = task % 5;
            const int* cp = &input[(gi0 + i) * 105 + w * 21 + 1];
            int c[20];
            #pragma unroll
            for (int p = 0; p < 20; ++p) c[p] = cp[p];
            h2v m[4];
            #pragma unroll
            for (int d = 0; d < 4; ++d) { m[d].x = (_Float16)(-30000.f); m[d].y = (_Float16)(-30000.f); }
            #pragma unroll 9
            for (int p = 0; p < 18; ++p) {
                uint4 rab = TBg[(c[p] * 100 + c[p + 1]) * 4 + q4];       // global 16B (L2)
                uint4 rc  = *(const uint4*)&T2[c[p + 2] * 20 + q4 * 4];  // LDS 16B
                unsigned int* pab = (unsigned int*)&rab;
                unsigned int* pc  = (unsigned int*)&rc;
                #pragma unroll
                for (int d = 0; d < 4; ++d) {
                    h2v s = u2h(pab[d]) + u2h(pc[d]);
                    m[d] = __builtin_elementwise_max(m[d], s);
                }
            }
            int base = i * 212 + w * 40 + 25 + q4 * 4;
            Fw[base]     = h2u(m[0] + bias[0]);
            Fw[base + 1] = h2u(m[1] + bias[1]);
            Fw[base + 2] = h2u(m[2] + bias[2]);
            if (q4 < 3) Fw[base + 3] = h2u(m[3] + bias[3]);
        }
    }

    // ---- preload A-frags (own-wave LDS writes are visible in-order) ----
    uint4 af[13];
    {
        const unsigned int* arow = &Fw[ln15 * 212 + quad * 4];
        #pragma unroll
        for (int ks = 0; ks < 13; ++ks) af[ks] = *(const uint4*)(arow + ks * 16);
    }

    // ---- fc1: B double-buffered through dead T region, 1 barrier per k-step ----
    f32x4 acc[7];
    #pragma unroll
    for (int t = 0; t < 7; ++t) acc[t] = f32x4{0, 0, 0, 0};

    uint4* Bb = (uint4*)Ths;
    __syncthreads();                       // (A) all conv reads of Ths done
    Bb[se] = p0; Bb[se + 64] = p1;         // buf0 <- ks0
    __syncthreads();                       // (B) buf0 visible

    #pragma unroll
    for (int ks = 0; ks < 13; ++ks) {
        uint4 n0, n1;
        if (ks < 12) {                     // issue next-chunk loads EARLY
            n0 = srcB[(ks + 1) * 512 + se];
            n1 = srcB[(ks + 1) * 512 + se + 64];
        }
        const uint4* bp = Bb + (ks & 1) * 512;
        half8 a = ash8(af[ks]);
        #pragma unroll
        for (int t = 0; t < 7; ++t)
            acc[t] = __builtin_amdgcn_mfma_f32_16x16x32_f16(a, ash8(bp[t * 64 + lane]), acc[t], 0, 0, 0);
        if (ks < 12) {                     // write LATE (load latency hidden by MFMAs)
            uint4* np = Bb + ((ks + 1) & 1) * 512;
            np[se] = n0; np[se + 64] = n1;
        }
        __syncthreads();
    }

    // ---- out-B staging loads (hidden under tanh epilogue) ----
    const uint4* srcO = (const uint4*)(ws + WS_OUT);
    uint4 o0 = srcO[wv * 192 + lane];
    uint4 o1 = srcO[wv * 192 + 64 + lane];
    uint4 o2 = srcO[wv * 192 + 128 + lane];

    // ---- epilogue: tanh -> Hh (aliased onto own F region; in-order DS, no barrier) ----
    unsigned int* Hw = Fw;
    {
        for (int t2 = lane; t2 < 224; t2 += 64) {
            int i = t2 / 14, d = t2 % 14;
            Hw[i * 68 + 50 + d] = 0;
        }
        unsigned short* Hs = (unsigned short*)Hw;
        #pragma unroll
        for (int t = 0; t < 7; ++t) {
            int j = t * 16 + ln15;
            if (j < HID) {
                float bj = fc1_b[j];
                #pragma unroll
                for (int r = 0; r < 4; ++r) {
                    int it = quad * 4 + r;
                    float hv = fast_tanh(acc[t][r] + bj);
                    _Float16 h = (_Float16)hv;
                    Hs[it * 136 + j] = *reinterpret_cast<unsigned short*>(&h);
                }
            }
        }
    }

    // ---- commit out-B to LDS, one barrier, then out MFMAs ----
    Bb[wv * 192 + lane]       = o0;
    Bb[wv * 192 + 64 + lane]  = o1;
    Bb[wv * 192 + 128 + lane] = o2;
    __syncthreads();

    {
        f32x4 oacc[3];
        #pragma unroll
        for (int t = 0; t < 3; ++t) oacc[t] = f32x4{0, 0, 0, 0};
        const int aoff = ln15 * 68 + quad * 4;
        #pragma unroll
        for (int ks = 0; ks < 4; ++ks) {
            half8 a = ash8(*(const uint4*)&Hw[aoff + ks * 16]);
            #pragma unroll
            for (int t = 0; t < 3; ++t) {
                uint4 bv = Bb[(ks * 3 + t) * 64 + lane];
                oacc[t] = __builtin_amdgcn_mfma_f32_16x16x32_f16(a, ash8(bv), oacc[t], 0, 0, 0);
            }
        }
        #pragma unroll
        for (int t = 0; t < 3; ++t) {
            int o = t * 16 + ln15;
            if (o < TAGS) {
                float bo = out_b[o];
                #pragma unroll
                for (int r = 0; r < 4; ++r) {
                    int it = gi0 + quad * 4 + r;
                    out[it * TAGS + o] = oacc[t][r] + bo;
                }
            }
        }
    }
}

extern "C" void kernel_launch(void* const* d_in, const int* in_sizes, int n_in,
                              void* d_out, int out_size, void* d_ws, size_t ws_size,
                              hipStream_t stream) {
    const int*   input  = (const int*)  d_in[0];
    const float* emb    = (const float*)d_in[1];
    const float* char_e = (const float*)d_in[2];
    const float* conv_w = (const float*)d_in[3];
    const float* conv_b = (const float*)d_in[4];
    const float* fc1_w  = (const float*)d_in[5];
    const float* fc1_b  = (const float*)d_in[6];
    const float* out_w  = (const float*)d_in[7];
    const float* out_b  = (const float*)d_in[8];
    unsigned int* ws = (unsigned int*)d_ws;

    prep<<<735, 256, 0, stream>>>(conv_w, char_e, fc1_w, out_w, ws);
    fused<<<B_TOT / 64, 256, 0, stream>>>(input, emb, conv_b, fc1_b, out_b, ws, (float*)d_out);
}

// Round 5
// 119.451 us; speedup vs baseline: 1.1104x; 1.1104x over previous
//
#include <hip/hip_runtime.h>

#define B_TOT 32768
#define OC 30
#define HID 100
#define TAGS 36

typedef __attribute__((ext_vector_type(8))) _Float16 half8;
typedef __attribute__((ext_vector_type(2))) _Float16 h2v;
typedef __attribute__((ext_vector_type(4))) float f32x4;

__device__ inline half8 ash8(uint4 u) {
    union { uint4 a; half8 b; } v; v.a = u; return v.b;
}
__device__ inline unsigned int h2u(h2v h) {
    union { h2v a; unsigned int b; } v; v.a = h; return v.b;
}
__device__ inline h2v u2h(unsigned int u) {
    union { unsigned int a; h2v b; } v; v.a = u; return v.b;
}
__device__ inline unsigned int pk_f16(float a, float b) {
    h2v h; h.x = (_Float16)a; h.y = (_Float16)b; return h2u(h);
}
__device__ inline uint4 pack8(float4 x, float4 y) {
    uint4 r;
    r.x = pk_f16(x.x, x.y);
    r.y = pk_f16(x.z, x.w);
    r.z = pk_f16(y.x, y.y);
    r.w = pk_f16(y.z, y.w);
    return r;
}
__device__ inline float fast_tanh(float x) {
    float ax = __builtin_fabsf(x);
    float e  = __expf(2.0f * ax);
    float r  = 1.0f - 2.0f * __builtin_amdgcn_rcpf(e + 1.0f);
    return __builtin_copysignf(r, x);
}

// ---- single fused kernel: T-build (MFMA) -> emb+conv -> fc1 MFMA (B staged from raw fc1_w) -> tanh -> out ----
__global__ __launch_bounds__(256, 2)
void fused(const int*   __restrict__ input,    // (B, 105)
           const float* __restrict__ emb,      // (WV, 50)
           const float* __restrict__ char_emb, // (100, 32)
           const float* __restrict__ conv_w,   // (30, 32, 3)
           const float* __restrict__ conv_b,   // (30)
           const float* __restrict__ fc1_w,    // (100, 400)
           const float* __restrict__ fc1_b,    // (100)
           const float* __restrict__ out_w,    // (36, 100)
           const float* __restrict__ out_b,    // (36)
           float*       __restrict__ out)      // (B, 36)
{
    __shared__ __align__(16) unsigned int Ths[6000];      // T tables [k][g][c][4]; after conv: B dbuf [2][512 u4]
    __shared__ __align__(16) unsigned int FL[64 * 212];   // F rows (212-dw stride)

    const int tid  = threadIdx.x;
    const int wv   = tid >> 6;
    const int lane = tid & 63;
    const int ln15 = lane & 15;
    const int quad = lane >> 4;
    const int gi0  = blockIdx.x * 64 + wv * 16;
    unsigned int* Fw = &FL[wv * (16 * 212)];

    const int se = wv * 128 + lane;            // fc1-B staging slot (+64 for 2nd)
    const int jA = (2 * wv) * 16 + ln15;       // staged n-tiles 2wv, 2wv+1
    const int jB = jA + 16;
    const int kq = quad * 8;                   // k-octet within a k-step
    const bool vA = (jA < HID), vB = (jB < HID);

    // ---- ks0 fc1-B prologue loads (raw f32; fly during T-build) ----
    float4 pa0{}, pa1{}, pb0{}, pb1{};
    if (vA) { pa0 = *(const float4*)&fc1_w[jA * 400 + kq]; pa1 = *(const float4*)&fc1_w[jA * 400 + kq + 4]; }
    if (vB) { pb0 = *(const float4*)&fc1_w[jB * 400 + kq]; pb1 = *(const float4*)&fc1_w[jB * 400 + kq + 4]; }

    // ---- in-block T-build via MFMA: T_k = char_emb(100x32) @ conv_w[:,:,k]^T ----
    // Ths layout (dwords): k*2000 + g*400 + c*4 + d ; dword rd=g*4+d holds oc pair (2rd,2rd+1)
    if (wv < 3) {
        const int kk = wv;
        half8 bfr[2];
        #pragma unroll
        for (int nt = 0; nt < 2; ++nt) {
            int oc = nt * 16 + ln15;
            union { h2v h[4]; half8 v; } u;
            #pragma unroll
            for (int d = 0; d < 4; ++d) {
                int ce = kq + d * 2;
                float a0 = (oc < OC) ? conv_w[(oc * 32 + ce) * 3 + kk]     : 0.f;
                float a1 = (oc < OC) ? conv_w[(oc * 32 + ce + 1) * 3 + kk] : 0.f;
                u.h[d].x = (_Float16)a0;
                u.h[d].y = (_Float16)a1;
            }
            bfr[nt] = u.v;
        }
        unsigned short* Tu = (unsigned short*)Ths;
        #pragma unroll
        for (int mt = 0; mt < 7; ++mt) {
            int c = mt * 16 + ln15;
            float4 e0 = {0,0,0,0}, e1 = {0,0,0,0};
            if (c < 100) {
                e0 = *(const float4*)&char_emb[c * 32 + kq];
                e1 = *(const float4*)&char_emb[c * 32 + kq + 4];
            }
            union { h2v h[4]; half8 v; } ua;
            ua.h[0].x = (_Float16)e0.x; ua.h[0].y = (_Float16)e0.y;
            ua.h[1].x = (_Float16)e0.z; ua.h[1].y = (_Float16)e0.w;
            ua.h[2].x = (_Float16)e1.x; ua.h[2].y = (_Float16)e1.y;
            ua.h[3].x = (_Float16)e1.z; ua.h[3].y = (_Float16)e1.w;
            #pragma unroll
            for (int nt = 0; nt < 2; ++nt) {
                f32x4 tc = f32x4{0, 0, 0, 0};
                tc = __builtin_amdgcn_mfma_f32_16x16x32_f16(ua.v, bfr[nt], tc, 0, 0, 0);
                int oc = nt * 16 + ln15;
                if (oc < OC) {
                    int g = oc >> 3, dd = (oc >> 1) & 3, e = oc & 1;
                    int ubase = kk * 4000 + g * 800 + dd * 2 + e;
                    #pragma unroll
                    for (int r = 0; r < 4; ++r) {
                        int cc = mt * 16 + quad * 4 + r;
                        if (cc < 100) {
                            union { _Float16 f; unsigned short s; } cvt;
                            cvt.f = (_Float16)tc[r];
                            Tu[ubase + cc * 8] = cvt.s;
                        }
                    }
                }
            }
        }
    }
    __syncthreads();                 // T visible to all waves

    uint4 p0 = pack8(pa0, pa1), p1 = pack8(pb0, pb1);

    // ---- zero K-pad dwords 200..207 of this wave's 16 rows ----
    #pragma unroll
    for (int r = 0; r < 2; ++r) {
        int idx = lane + r * 64;
        Fw[(idx >> 3) * 212 + 200 + (idx & 7)] = 0;
    }

    // ---- word embeddings (own 16 items) ----
    #pragma unroll 4
    for (int idx = lane; idx < 2000; idx += 64) {
        int ph = idx % 25;
        int w  = (idx / 25) % 5;
        int i  = idx / 125;
        int wid = input[(gi0 + i) * 105 + w * 21];
        float2 e = *(const float2*)&emb[wid * 50 + ph * 2];
        Fw[i * 212 + w * 40 + ph] = pk_f16(e.x, e.y);
    }

    // ---- conv + maxpool: 4 lanes per (i,w), lane = 8 oc; 5 tasks per lane ----
    {
        const int q4  = lane & 3;
        const int oc0 = q4 * 8;
        h2v bias[4];
        #pragma unroll
        for (int d = 0; d < 4; ++d) {
            int a = oc0 + 2 * d, b = a + 1;
            bias[d].x = (_Float16)(a < OC ? conv_b[a] : 0.f);
            bias[d].y = (_Float16)(b < OC ? conv_b[b] : 0.f);
        }
        const unsigned int* T0 = &Ths[q4 * 400];
        const unsigned int* T1 = &Ths[q4 * 400 + 2000];
        const unsigned int* T2 = &Ths[q4 * 400 + 4000];
        #pragma unroll
        for (int it = 0; it < 5; ++it) {
            int task = (lane >> 2) + it * 16;   // 0..79
            int i = task / 5, w = task % 5;
            const int* cp = &input[(gi0 + i) * 105 + w * 21 + 1];
            int c[20];
            #pragma unroll
            for (int p = 0; p < 20; ++p) c[p] = cp[p];
            h2v m[4];
            #pragma unroll
            for (int d = 0; d < 4; ++d) { m[d].x = (_Float16)(-30000.f); m[d].y = (_Float16)(-30000.f); }
            #pragma unroll 6
            for (int p = 0; p < 18; ++p) {
                uint4 ra = *(const uint4*)&T0[c[p    ] * 4];
                uint4 rb = *(const uint4*)&T1[c[p + 1] * 4];
                uint4 rc = *(const uint4*)&T2[c[p + 2] * 4];
                unsigned int* pa = (unsigned int*)&ra;
                unsigned int* pb = (unsigned int*)&rb;
                unsigned int* pc = (unsigned int*)&rc;
                #pragma unroll
                for (int d = 0; d < 4; ++d) {
                    h2v s = u2h(pa[d]) + u2h(pb[d]) + u2h(pc[d]);
                    m[d] = __builtin_elementwise_max(m[d], s);
                }
            }
            int base = i * 212 + w * 40 + 25 + q4 * 4;
            Fw[base]     = h2u(m[0] + bias[0]);
            Fw[base + 1] = h2u(m[1] + bias[1]);
            Fw[base + 2] = h2u(m[2] + bias[2]);
            if (q4 < 3) Fw[base + 3] = h2u(m[3] + bias[3]);
        }
    }

    // ---- preload A-frags (own-wave LDS writes are visible in-order) ----
    uint4 af[13];
    {
        const unsigned int* arow = &Fw[ln15 * 212 + quad * 4];
        #pragma unroll
        for (int ks = 0; ks < 13; ++ks) af[ks] = *(const uint4*)(arow + ks * 16);
    }

    // ---- fc1: B double-buffered through dead T region, staged from raw fc1_w ----
    f32x4 acc[7];
    #pragma unroll
    for (int t = 0; t < 7; ++t) acc[t] = f32x4{0, 0, 0, 0};

    uint4* Bb = (uint4*)Ths;
    __syncthreads();                       // (A) all conv reads of Ths done
    Bb[se] = p0; Bb[se + 64] = p1;         // buf0 <- ks0
    __syncthreads();                       // (B) buf0 visible

    #pragma unroll
    for (int ks = 0; ks < 13; ++ks) {
        float4 na0{}, na1{}, nb0{}, nb1{};
        if (ks < 12) {                     // issue next-chunk raw loads EARLY
            const int kb = (ks + 1) * 32 + kq;
            const bool kv = (ks < 11) || (kq <= 8);   // k-step 12 valid only for kq<=8
            if (vA && kv) { na0 = *(const float4*)&fc1_w[jA * 400 + kb]; na1 = *(const float4*)&fc1_w[jA * 400 + kb + 4]; }
            if (vB && kv) { nb0 = *(const float4*)&fc1_w[jB * 400 + kb]; nb1 = *(const float4*)&fc1_w[jB * 400 + kb + 4]; }
        }
        const uint4* bp = Bb + (ks & 1) * 512;
        half8 a = ash8(af[ks]);
        #pragma unroll
        for (int t = 0; t < 7; ++t)
            acc[t] = __builtin_amdgcn_mfma_f32_16x16x32_f16(a, ash8(bp[t * 64 + lane]), acc[t], 0, 0, 0);
        if (ks < 12) {                     // cvt + write LATE (load latency hidden by MFMAs)
            uint4* np = Bb + ((ks + 1) & 1) * 512;
            np[se]      = pack8(na0, na1);
            np[se + 64] = pack8(nb0, nb1);
        }
        __syncthreads();
    }

    // ---- out-B staging loads from raw out_w (hidden under tanh epilogue) ----
    uint4 og[3];
    {
        const int ko = wv * 32 + kq;        // this wave stages k-step wv, n-tiles 0..2
        #pragma unroll
        for (int nt = 0; nt < 3; ++nt) {
            int j = nt * 16 + ln15;
            unsigned int dws[4];
            #pragma unroll
            for (int dw = 0; dw < 4; ++dw) {
                int kk = ko + dw * 2;
                float a = (j < TAGS && kk     < HID) ? out_w[j * 100 + kk]     : 0.f;
                float b = (j < TAGS && kk + 1 < HID) ? out_w[j * 100 + kk + 1] : 0.f;
                dws[dw] = pk_f16(a, b);
            }
            og[nt].x = dws[0]; og[nt].y = dws[1]; og[nt].z = dws[2]; og[nt].w = dws[3];
        }
    }

    // ---- epilogue: tanh -> Hh (aliased onto own F region; in-order DS, no barrier) ----
    unsigned int* Hw = Fw;
    {
        for (int t2 = lane; t2 < 224; t2 += 64) {
            int i = t2 / 14, d = t2 % 14;
            Hw[i * 68 + 50 + d] = 0;
        }
        unsigned short* Hs = (unsigned short*)Hw;
        #pragma unroll
        for (int t = 0; t < 7; ++t) {
            int j = t * 16 + ln15;
            if (j < HID) {
                float bj = fc1_b[j];
                #pragma unroll
                for (int r = 0; r < 4; ++r) {
                    int it = quad * 4 + r;
                    float hv = fast_tanh(acc[t][r] + bj);
                    _Float16 h = (_Float16)hv;
                    Hs[it * 136 + j] = *reinterpret_cast<unsigned short*>(&h);
                }
            }
        }
    }

    // ---- commit out-B to LDS, one barrier, then out MFMAs ----
    Bb[wv * 192 + lane]       = og[0];
    Bb[wv * 192 + 64 + lane]  = og[1];
    Bb[wv * 192 + 128 + lane] = og[2];
    __syncthreads();

    {
        f32x4 oacc[3];
        #pragma unroll
        for (int t = 0; t < 3; ++t) oacc[t] = f32x4{0, 0, 0, 0};
        const int aoff = ln15 * 68 + quad * 4;
        #pragma unroll
        for (int ks = 0; ks < 4; ++ks) {
            half8 a = ash8(*(const uint4*)&Hw[aoff + ks * 16]);
            #pragma unroll
            for (int t = 0; t < 3; ++t) {
                uint4 bv = Bb[(ks * 3 + t) * 64 + lane];
                oacc[t] = __builtin_amdgcn_mfma_f32_16x16x32_f16(a, ash8(bv), oacc[t], 0, 0, 0);
            }
        }
        #pragma unroll
        for (int t = 0; t < 3; ++t) {
            int o = t * 16 + ln15;
            if (o < TAGS) {
                float bo = out_b[o];
                #pragma unroll
                for (int r = 0; r < 4; ++r) {
                    int it = gi0 + quad * 4 + r;
                    out[it * TAGS + o] = oacc[t][r] + bo;
                }
            }
        }
    }
}

extern "C" void kernel_launch(void* const* d_in, const int* in_sizes, int n_in,
                              void* d_out, int out_size, void* d_ws, size_t ws_size,
                              hipStream_t stream) {
    const int*   input  = (const int*)  d_in[0];
    const float* emb    = (const float*)d_in[1];
    const float* char_e = (const float*)d_in[2];
    const float* conv_w = (const float*)d_in[3];
    const float* conv_b = (const float*)d_in[4];
    const float* fc1_w  = (const float*)d_in[5];
    const float* fc1_b  = (const float*)d_in[6];
    const float* out_w  = (const float*)d_in[7];
    const float* out_b  = (const float*)d_in[8];

    fused<<<B_TOT / 64, 256, 0, stream>>>(input, emb, char_e, conv_w, conv_b,
                                          fc1_w, fc1_b, out_w, out_b, (float*)d_out);
}

// Round 6
// 110.146 us; speedup vs baseline: 1.2042x; 1.0845x over previous
//
#include <hip/hip_runtime.h>

#define B_TOT 32768
#define OC 30
#define HID 100
#define TAGS 36

// ws layout (dwords):
#define WS_TH  0          // fp16x2[6000]   T tables: ((k*5+g)*100+c)*4+d
#define WS_FC1 6000       // u32[13*2048]   fc1 B packs, ks-major, 2048-dw stride (1792 used/ks)
#define WS_OUT 32624      // u32[3072]      out B packs, ks-major: chunk = ks*3+nt

typedef __attribute__((ext_vector_type(8))) _Float16 half8;
typedef __attribute__((ext_vector_type(2))) _Float16 h2v;
typedef __attribute__((ext_vector_type(4))) float f32x4;

struct __attribute__((packed, aligned(4))) U4A { uint4 v; };   // 4-B-aligned uint4 load

__device__ inline half8 ash8(uint4 u) {
    union { uint4 a; half8 b; } v; v.a = u; return v.b;
}
__device__ inline unsigned int h2u(h2v h) {
    union { h2v a; unsigned int b; } v; v.a = h; return v.b;
}
__device__ inline h2v u2h(unsigned int u) {
    union { unsigned int a; h2v b; } v; v.a = u; return v.b;
}
__device__ inline unsigned int pk_f16(float a, float b) {
    h2v h; h.x = (_Float16)a; h.y = (_Float16)b; return h2u(h);
}
__device__ inline float fast_tanh(float x) {
    float ax = __builtin_fabsf(x);
    float e  = __expf(2.0f * ax);
    float r  = 1.0f - 2.0f * __builtin_amdgcn_rcpf(e + 1.0f);
    return __builtin_copysignf(r, x);
}

// ---------------- prep: fp16 T tables + fp16 MFMA B-frag packs (R2-proven) ----------------
__global__ void prep(const float* __restrict__ conv_w,   // (30,32,3)
                     const float* __restrict__ char_emb, // (100,32)
                     const float* __restrict__ fc1_w,    // (100,400)
                     const float* __restrict__ out_w,    // (36,100)
                     unsigned int* __restrict__ ws) {
    int idx = blockIdx.x * 256 + threadIdx.x;
    if (idx < 6000) {
        // T layout: ((k*5+g)*100+c)*4+d ; dword rd = g*4+d holds oc pair (2rd, 2rd+1)
        int d  = idx & 3;
        int t  = idx >> 2;        // 0..1499
        int c  = t % 100;
        int kg = t / 100;         // 0..14
        int g  = kg % 5, k = kg / 5;
        int rd = g * 4 + d;       // 0..19
        float v[2];
        #pragma unroll
        for (int e = 0; e < 2; ++e) {
            int oc = rd * 2 + e;
            float s = 0.f;
            if (oc < OC) {
                for (int ce = 0; ce < 32; ++ce)
                    s += char_emb[c * 32 + ce] * conv_w[(oc * 32 + ce) * 3 + k];
            }
            v[e] = s;
        }
        ws[WS_TH + idx] = pk_f16(v[0], v[1]);
    } else if (idx < 6000 + 23296) {
        // fc1 B-frag chunks, ks-major: region ks*2048 + (nt*64+lane)*4+dw
        int t = idx - 6000;
        int dw = t & 3, lane = (t >> 2) & 63, chunk = t >> 8;   // chunk 0..90
        int ks = chunk / 7, nt = chunk % 7;
        int j = nt * 16 + (lane & 15);
        int k = ks * 32 + (lane >> 4) * 8 + dw * 2;
        float a = (j < HID && k     < 400) ? fc1_w[j * 400 + k]     : 0.f;
        float b = (j < HID && k + 1 < 400) ? fc1_w[j * 400 + k + 1] : 0.f;
        ws[WS_FC1 + ks * 2048 + (nt * 64 + lane) * 4 + dw] = pk_f16(a, b);
    } else if (idx < 29296 + 3072) {
        // out B-frag chunks, ks-major: chunk = ks*3+nt, linear
        int t = idx - 29296;
        int dw = t & 3, lane = (t >> 2) & 63, chunk = t >> 8;   // chunk 0..11
        int ks = chunk / 3, nt = chunk % 3;
        int j = nt * 16 + (lane & 15);
        int k = ks * 32 + (lane >> 4) * 8 + dw * 2;
        float a = (j < TAGS && k     < HID) ? out_w[j * 100 + k]     : 0.f;
        float b = (j < TAGS && k + 1 < HID) ? out_w[j * 100 + k + 1] : 0.f;
        ws[WS_OUT + t] = pk_f16(a, b);
    }
}

// ---------------- fused: emb+conv -> F in LDS -> fc1 MFMA (B staged in LDS) -> tanh -> out ----------------
__global__ __launch_bounds__(256, 2)
void fused(const int*   __restrict__ input,   // (B, 105)
           const float* __restrict__ emb,     // (WV, 50)
           const float* __restrict__ conv_b,  // (30)
           const float* __restrict__ fc1_b,   // (100)
           const float* __restrict__ out_b,   // (36)
           const unsigned int* __restrict__ ws,
           float*       __restrict__ out)     // (B, 36)
{
    __shared__ __align__(16) unsigned int Ths[6000];      // T tables; after conv: B dbuf [2][512 u4] / out-B
    __shared__ __align__(16) unsigned int FL[64 * 212];   // F rows (212-dw stride)

    const int tid  = threadIdx.x;
    const int wv   = tid >> 6;
    const int lane = tid & 63;
    const int ln15 = lane & 15;
    const int quad = lane >> 4;
    const int gi0  = blockIdx.x * 64 + wv * 16;
    unsigned int* Fw = &FL[wv * (16 * 212)];

    const uint4* srcB = (const uint4*)(ws + WS_FC1);      // uint4 idx: ks*512 + e
    const int se = wv * 128 + lane;                       // this wave's staging slot (+64 for 2nd)

    // ---- stage T tables (block-wide, vectorized) ----
    {
        const uint4* src = (const uint4*)(ws + WS_TH);
        uint4* dst = (uint4*)Ths;
        for (int idx = tid; idx < 1500; idx += 256) dst[idx] = src[idx];
    }
    // prologue B loads for ks=0 (pure global loads, fly during emb/conv)
    uint4 p0 = srcB[se], p1 = srcB[se + 64];
    __syncthreads();

    // ---- zero K-pad dwords 200..207 of this wave's 16 rows ----
    #pragma unroll
    for (int r = 0; r < 2; ++r) {
        int idx = lane + r * 64;
        Fw[(idx >> 3) * 212 + 200 + (idx & 7)] = 0;
    }

    // ---- word embeddings: two-pass (all wid loads issued, then all gathers) ----
    {
        int wid[32];
        #pragma unroll
        for (int j = 0; j < 32; ++j) {
            int idx = lane + j * 64;
            if (idx < 2000) {
                int w = (idx / 25) % 5;
                int i = idx / 125;
                wid[j] = input[(gi0 + i) * 105 + w * 21];
            }
        }
        #pragma unroll
        for (int j = 0; j < 32; ++j) {
            int idx = lane + j * 64;
            if (idx < 2000) {
                int ph = idx % 25;
                int w  = (idx / 25) % 5;
                int i  = idx / 125;
                float2 e = *(const float2*)&emb[wid[j] * 50 + ph * 2];
                Fw[i * 212 + w * 40 + ph] = pk_f16(e.x, e.y);
            }
        }
    }

    // ---- conv + maxpool: 4 lanes per (i,w), lane = 8 oc; 5 tasks per lane ----
    {
        const int q4  = lane & 3;
        const int oc0 = q4 * 8;
        h2v bias[4];
        #pragma unroll
        for (int d = 0; d < 4; ++d) {
            int a = oc0 + 2 * d, b = a + 1;
            bias[d].x = (_Float16)(a < OC ? conv_b[a] : 0.f);
            bias[d].y = (_Float16)(b < OC ? conv_b[b] : 0.f);
        }
        const unsigned int* T0 = &Ths[q4 * 400];
        const unsigned int* T1 = &Ths[q4 * 400 + 2000];
        const unsigned int* T2 = &Ths[q4 * 400 + 4000];

        const int tk = lane >> 2;
        // char loads: 5x dwordx4 (4-B-aligned wrapper), depth-1 prefetch across tasks
        uint4 cvA0, cvA1, cvA2, cvA3, cvA4;
        {
            const U4A* q = (const U4A*)&input[(gi0 + tk / 5) * 105 + (tk % 5) * 21 + 1];
            cvA0 = q[0].v; cvA1 = q[1].v; cvA2 = q[2].v; cvA3 = q[3].v; cvA4 = q[4].v;
        }
        #pragma unroll
        for (int it = 0; it < 5; ++it) {
            int task = tk + it * 16;            // 0..79
            int i = task / 5, w = task % 5;
            uint4 cvB0, cvB1, cvB2, cvB3, cvB4;
            if (it < 4) {                       // issue next task's chars EARLY
                int tn = tk + (it + 1) * 16;
                const U4A* q = (const U4A*)&input[(gi0 + tn / 5) * 105 + (tn % 5) * 21 + 1];
                cvB0 = q[0].v; cvB1 = q[1].v; cvB2 = q[2].v; cvB3 = q[3].v; cvB4 = q[4].v;
            }
            int c[20];
            c[0]=cvA0.x; c[1]=cvA0.y; c[2]=cvA0.z; c[3]=cvA0.w;
            c[4]=cvA1.x; c[5]=cvA1.y; c[6]=cvA1.z; c[7]=cvA1.w;
            c[8]=cvA2.x; c[9]=cvA2.y; c[10]=cvA2.z; c[11]=cvA2.w;
            c[12]=cvA3.x; c[13]=cvA3.y; c[14]=cvA3.z; c[15]=cvA3.w;
            c[16]=cvA4.x; c[17]=cvA4.y; c[18]=cvA4.z; c[19]=cvA4.w;
            h2v m[4];
            #pragma unroll
            for (int d = 0; d < 4; ++d) { m[d].x = (_Float16)(-30000.f); m[d].y = (_Float16)(-30000.f); }
            #pragma unroll
            for (int p = 0; p < 18; ++p) {
                uint4 ra = *(const uint4*)&T0[c[p    ] * 4];
                uint4 rb = *(const uint4*)&T1[c[p + 1] * 4];
                uint4 rc = *(const uint4*)&T2[c[p + 2] * 4];
                unsigned int* pa = (unsigned int*)&ra;
                unsigned int* pb = (unsigned int*)&rb;
                unsigned int* pc = (unsigned int*)&rc;
                #pragma unroll
                for (int d = 0; d < 4; ++d) {
                    h2v s = u2h(pa[d]) + u2h(pb[d]) + u2h(pc[d]);
                    m[d] = __builtin_elementwise_max(m[d], s);
                }
            }
            int base = i * 212 + w * 40 + 25 + q4 * 4;
            Fw[base]     = h2u(m[0] + bias[0]);
            Fw[base + 1] = h2u(m[1] + bias[1]);
            Fw[base + 2] = h2u(m[2] + bias[2]);
            if (q4 < 3) Fw[base + 3] = h2u(m[3] + bias[3]);
            cvA0 = cvB0; cvA1 = cvB1; cvA2 = cvB2; cvA3 = cvB3; cvA4 = cvB4;
        }
    }

    // ---- preload A-frags (own-wave LDS writes are visible in-order) ----
    uint4 af[13];
    {
        const unsigned int* arow = &Fw[ln15 * 212 + quad * 4];
        #pragma unroll
        for (int ks = 0; ks < 13; ++ks) af[ks] = *(const uint4*)(arow + ks * 16);
    }

    // ---- fc1: B double-buffered through dead T region, 1 barrier per k-step ----
    f32x4 acc[7];
    #pragma unroll
    for (int t = 0; t < 7; ++t) acc[t] = f32x4{0, 0, 0, 0};

    uint4* Bb = (uint4*)Ths;
    __syncthreads();                       // (A) all conv reads of Ths done
    Bb[se] = p0; Bb[se + 64] = p1;         // buf0 <- ks0
    __syncthreads();                       // (B) buf0 visible

    #pragma unroll
    for (int ks = 0; ks < 13; ++ks) {
        uint4 n0, n1;
        if (ks < 12) {                     // issue next-chunk loads EARLY
            n0 = srcB[(ks + 1) * 512 + se];
            n1 = srcB[(ks + 1) * 512 + se + 64];
        }
        const uint4* bp = Bb + (ks & 1) * 512;
        half8 a = ash8(af[ks]);
        #pragma unroll
        for (int t = 0; t < 7; ++t)
            acc[t] = __builtin_amdgcn_mfma_f32_16x16x32_f16(a, ash8(bp[t * 64 + lane]), acc[t], 0, 0, 0);
        if (ks < 12) {                     // write LATE (load latency hidden by MFMAs)
            uint4* np = Bb + ((ks + 1) & 1) * 512;
            np[se] = n0; np[se + 64] = n1;
        }
        __syncthreads();
    }

    // ---- out-B staging loads (hidden under tanh epilogue) ----
    const uint4* srcO = (const uint4*)(ws + WS_OUT);
    uint4 o0 = srcO[wv * 192 + lane];
    uint4 o1 = srcO[wv * 192 + 64 + lane];
    uint4 o2 = srcO[wv * 192 + 128 + lane];

    // ---- epilogue: tanh -> Hh (aliased onto own F region; in-order DS, no barrier) ----
    unsigned int* Hw = Fw;
    {
        for (int t2 = lane; t2 < 224; t2 += 64) {
            int i = t2 / 14, d = t2 % 14;
            Hw[i * 68 + 50 + d] = 0;
        }
        unsigned short* Hs = (unsigned short*)Hw;
        #pragma unroll
        for (int t = 0; t < 7; ++t) {
            int j = t * 16 + ln15;
            if (j < HID) {
                float bj = fc1_b[j];
                #pragma unroll
                for (int r = 0; r < 4; ++r) {
                    int it = quad * 4 + r;
                    float hv = fast_tanh(acc[t][r] + bj);
                    _Float16 h = (_Float16)hv;
                    Hs[it * 136 + j] = *reinterpret_cast<unsigned short*>(&h);
                }
            }
        }
    }

    // ---- commit out-B to LDS, one barrier, then out MFMAs ----
    Bb[wv * 192 + lane]       = o0;
    Bb[wv * 192 + 64 + lane]  = o1;
    Bb[wv * 192 + 128 + lane] = o2;
    __syncthreads();

    {
        f32x4 oacc[3];
        #pragma unroll
        for (int t = 0; t < 3; ++t) oacc[t] = f32x4{0, 0, 0, 0};
        const int aoff = ln15 * 68 + quad * 4;
        #pragma unroll
        for (int ks = 0; ks < 4; ++ks) {
            half8 a = ash8(*(const uint4*)&Hw[aoff + ks * 16]);
            #pragma unroll
            for (int t = 0; t < 3; ++t) {
                uint4 bv = Bb[(ks * 3 + t) * 64 + lane];
                oacc[t] = __builtin_amdgcn_mfma_f32_16x16x32_f16(a, ash8(bv), oacc[t], 0, 0, 0);
            }
        }
        #pragma unroll
        for (int t = 0; t < 3; ++t) {
            int o = t * 16 + ln15;
            if (o < TAGS) {
                float bo = out_b[o];
                #pragma unroll
                for (int r = 0; r < 4; ++r) {
                    int it = gi0 + quad * 4 + r;
                    out[it * TAGS + o] = oacc[t][r] + bo;
                }
            }
        }
    }
}

extern "C" void kernel_launch(void* const* d_in, const int* in_sizes, int n_in,
                              void* d_out, int out_size, void* d_ws, size_t ws_size,
                              hipStream_t stream) {
    const int*   input  = (const int*)  d_in[0];
    const float* emb    = (const float*)d_in[1];
    const float* char_e = (const float*)d_in[2];
    const float* conv_w = (const float*)d_in[3];
    const float* conv_b = (const float*)d_in[4];
    const float* fc1_w  = (const float*)d_in[5];
    const float* fc1_b  = (const float*)d_in[6];
    const float* out_w  = (const float*)d_in[7];
    const float* out_b  = (const float*)d_in[8];
    unsigned int* ws = (unsigned int*)d_ws;

    prep<<<127, 256, 0, stream>>>(conv_w, char_e, fc1_w, out_w, ws);
    fused<<<B_TOT / 64, 256, 0, stream>>>(input, emb, conv_b, fc1_b, out_b, ws, (float*)d_out);
}